// Round 1
// baseline (563.037 us; speedup 1.0000x reference)
//
#include <hip/hip_runtime.h>
#include <cstdint>
#include <cstddef>

#define HW    262144          // 512*512
#define C     64
#define K     19
#define NPIX  1048576
#define TAUINV (1.0f / 0.07f)
#define EPS   1e-12f

#define NCHUNK64 (NPIX / 64)  // 16384 chunks of 64 pixels
#define CPB64    (HW / 64)    // 4096 chunks per batch image
#define G1       256          // k1 blocks (x16 waves = 4096 waves, 4 chunks/wave)

// ws layout:
//   +0     unsigned num_pos
//   +4     float    loss_sum
//   +256   float    k0p[32*64]   (8 KB, classes padded to 32)
//   +8448  float    k0n[19*64]
//   +65536 unsigned pm[NPIX]     (4 MB)

typedef __attribute__((ext_vector_type(8))) short bf16x8;
typedef __attribute__((ext_vector_type(4))) float f32x4;

__device__ __forceinline__ float wave_reduce_f32(float v) {
#pragma unroll
    for (int off = 32; off; off >>= 1) v += __shfl_down(v, off);
    return v;
}
__device__ __forceinline__ unsigned wave_reduce_u32(unsigned v) {
#pragma unroll
    for (int off = 32; off; off >>= 1) v += __shfl_down(v, off);
    return v;
}

// RNE f32 -> (bf16 hi, bf16 lo): hi+lo represents f to ~2^-16 relative
__device__ __forceinline__ void split1(float f, short& h, short& l) {
    const unsigned u  = __float_as_uint(f);
    const unsigned hb = (u + 0x7FFFu + ((u >> 16) & 1u)) & 0xFFFF0000u;
    h = (short)(hb >> 16);
    const float lo = f - __uint_as_float(hb);
    const unsigned v = __float_as_uint(lo);
    l = (short)((v + 0x7FFFu + ((v >> 16) & 1u)) >> 16);
}

// ---------------- Kernel 1: MFMA prototypes k0p[32][64] + masks -----------
// 64-px chunks: every lane owns one pixel -> gt loads and pm stores are
// full-wave 256B coalesced (was half-wave 128B). K-dim = pixels, 2 K-steps
// of 32 per chunk. Mask exact in bf16; feat split hi/lo (2 MFMAs each).
__global__ __launch_bounds__(1024) void k1_proto(
    const float* __restrict__ feat, const int* __restrict__ gt,
    unsigned* __restrict__ pm,
    float* __restrict__ k0p, unsigned* __restrict__ num_pos)
{
    __shared__ float red[32 * 64];        // 8 KB block-reduce buffer
    const int tid  = threadIdx.x;
    const int lane = tid & 63;
    const int wv   = tid >> 6;            // 0..15
    const int q    = lane >> 4;           // quad 0..3
    const int n    = lane & 15;           // n/col within fragment
    const int q8   = q << 3;              // this quad's k-offset within K-step

    f32x4 acc[2][4];
#pragma unroll
    for (int mt = 0; mt < 2; ++mt)
#pragma unroll
        for (int nt = 0; nt < 4; ++nt)
            acc[mt][nt] = (f32x4){0.f, 0.f, 0.f, 0.f};
    unsigned npos = 0;

    const int wave_id = blockIdx.x * 16 + wv;
    const int nwaves  = G1 * 16;          // 4096

    for (int chunk = wave_id; chunk < NCHUNK64; chunk += nwaves) {
        const int b   = chunk >> 12;                 // / CPB64
        const int hw0 = (chunk & (CPB64 - 1)) << 6;
        const size_t fbase = (size_t)b * C * HW + hw0;

        // ---- packed masks: all 64 lanes own one pixel each (256B coalesced)
        unsigned mymask = 0;
        {
            const int* gp = gt + (size_t)b * K * HW + hw0 + lane;
#pragma unroll
            for (int k = 0; k < K; ++k)
                mymask |= (gp[(size_t)k * HW] == 1) ? (1u << k) : 0u;
        }
        pm[(size_t)chunk * 64 + lane] = mymask;
        npos += __popc(mymask);

        // ---- two K-steps of 32 pixels each
#pragma unroll
        for (int s = 0; s < 2; ++s) {
            // A fragments (mask): lane holds class row m=n (tile0) / n+16
            // (tile1), k-slot j -> pixel s*32 + q8 + j. Bits -> bf16 {0,1.0}.
            unsigned w8[8];
#pragma unroll
            for (int j = 0; j < 8; ++j) w8[j] = __shfl(mymask, s * 32 + q8 + j);
            bf16x8 a0, a1;
#pragma unroll
            for (int j = 0; j < 8; ++j) {
                a0[j] = (short)(((w8[j] >> n) & 1u) * 0x3F80u);
                a1[j] = (short)(((w8[j] >> (n + 16)) & 1u) * 0x3F80u);
            }

            // B fragments (feat hi/lo) + MFMA, per 16-channel N-tile
            const float* fp = feat + fbase + (size_t)n * HW + s * 32 + q8;
#pragma unroll
            for (int nt = 0; nt < 4; ++nt) {
                const float* p = fp + (size_t)(nt * 16) * HW;
                const float4 x = *(const float4*)p;
                const float4 y = *(const float4*)(p + 4);
                bf16x8 bh, bl;
                {
                    short h, l;
                    split1(x.x, h, l); bh[0] = h; bl[0] = l;
                    split1(x.y, h, l); bh[1] = h; bl[1] = l;
                    split1(x.z, h, l); bh[2] = h; bl[2] = l;
                    split1(x.w, h, l); bh[3] = h; bl[3] = l;
                    split1(y.x, h, l); bh[4] = h; bl[4] = l;
                    split1(y.y, h, l); bh[5] = h; bl[5] = l;
                    split1(y.z, h, l); bh[6] = h; bl[6] = l;
                    split1(y.w, h, l); bh[7] = h; bl[7] = l;
                }
                acc[0][nt] = __builtin_amdgcn_mfma_f32_16x16x32_bf16(a0, bh, acc[0][nt], 0, 0, 0);
                acc[0][nt] = __builtin_amdgcn_mfma_f32_16x16x32_bf16(a0, bl, acc[0][nt], 0, 0, 0);
                acc[1][nt] = __builtin_amdgcn_mfma_f32_16x16x32_bf16(a1, bh, acc[1][nt], 0, 0, 0);
                acc[1][nt] = __builtin_amdgcn_mfma_f32_16x16x32_bf16(a1, bl, acc[1][nt], 0, 0, 0);
            }
        }
    }

    // ---- block reduce (D layout: class = mt*16 + q*4 + r, ch = nt*16 + n)
    for (int w = 0; w < 16; ++w) {
        if (wv == w) {
#pragma unroll
            for (int mt = 0; mt < 2; ++mt)
#pragma unroll
                for (int nt = 0; nt < 4; ++nt)
#pragma unroll
                    for (int r = 0; r < 4; ++r) {
                        const int idx = (mt * 16 + q * 4 + r) * 64 + nt * 16 + n;
                        if (w == 0) red[idx]  = acc[mt][nt][r];
                        else        red[idx] += acc[mt][nt][r];
                    }
        }
        __syncthreads();
    }
    // only the 19 real classes (rows 19..31 are identically zero)
    for (int i = tid; i < K * 64; i += 1024)
        atomicAdd(&k0p[i], red[i]);

    const unsigned np = wave_reduce_u32(npos);
    if (lane == 0) atomicAdd(num_pos, np);
}

// ---------------- Kernel 2: normalize prototypes --------------------------
__global__ __launch_bounds__(256) void k2_norm(
    const float* __restrict__ k0p, float* __restrict__ k0n)
{
    __shared__ float rn[K];
    const int tid  = threadIdx.x;
    const int lane = tid & 63;
    const int wv   = tid >> 6;
    for (int cls = wv; cls < K; cls += 4) {
        const float v = k0p[cls * 64 + lane];
        const float s = wave_reduce_f32(v * v);
        if (lane == 0) rn[cls] = 1.0f / fmaxf(sqrtf(s), EPS);
    }
    __syncthreads();
    for (int i = tid; i < K * 64; i += 256) k0n[i] = k0p[i] * rn[i >> 6];
}

// ---------------- Kernel 3: logits + log-softmax + masked NLL -------------
__global__ __launch_bounds__(256) void k3_loss(
    const float* __restrict__ feat, const int* __restrict__ gt,
    const unsigned* __restrict__ pm, const float* __restrict__ k0n,
    float* __restrict__ loss_sum)
{
    __shared__ __align__(16) float w[K * 64];
    const int tid = threadIdx.x;
    for (int i = tid; i < K * 64; i += 256) w[i] = k0n[i];
    __syncthreads();

    const int px0 = (blockIdx.x * 256 + tid) << 2;
    const int b   = px0 >> 18;
    const int hw  = px0 & (HW - 1);
    const float* fb = feat + (size_t)b * C * HW + hw;

    unsigned marr[4];
    {
        const uint4 mv = *(const uint4*)(pm + px0);
        marr[0] = mv.x; marr[1] = mv.y; marr[2] = mv.z; marr[3] = mv.w;
    }

    float4 dot[K];
#pragma unroll
    for (int k = 0; k < K; ++k) dot[k] = make_float4(0.f, 0.f, 0.f, 0.f);
    float4 ss = make_float4(0.f, 0.f, 0.f, 0.f);

    float4 f[8];
#pragma unroll
    for (int j = 0; j < 8; ++j)
        f[j] = *(const float4*)(fb + (size_t)j * HW);

#pragma unroll
    for (int cg = 0; cg < 64; cg += 8) {
        float4 g[8];
        if (cg + 8 < 64) {
#pragma unroll
            for (int j = 0; j < 8; ++j)
                g[j] = *(const float4*)(fb + (size_t)(cg + 8 + j) * HW);
        }
#pragma unroll
        for (int j = 0; j < 8; ++j) {
            const float4 fv = f[j];
            ss.x = fmaf(fv.x, fv.x, ss.x); ss.y = fmaf(fv.y, fv.y, ss.y);
            ss.z = fmaf(fv.z, fv.z, ss.z); ss.w = fmaf(fv.w, fv.w, ss.w);
        }
#pragma unroll
        for (int k = 0; k < K; ++k) {
            const float4 wa = *(const float4*)&w[k * 64 + cg];
            const float4 wb = *(const float4*)&w[k * 64 + cg + 4];
            float4 d = dot[k];
            d.x = fmaf(f[0].x, wa.x, d.x); d.y = fmaf(f[0].y, wa.x, d.y);
            d.z = fmaf(f[0].z, wa.x, d.z); d.w = fmaf(f[0].w, wa.x, d.w);
            d.x = fmaf(f[1].x, wa.y, d.x); d.y = fmaf(f[1].y, wa.y, d.y);
            d.z = fmaf(f[1].z, wa.y, d.z); d.w = fmaf(f[1].w, wa.y, d.w);
            d.x = fmaf(f[2].x, wa.z, d.x); d.y = fmaf(f[2].y, wa.z, d.y);
            d.z = fmaf(f[2].z, wa.z, d.z); d.w = fmaf(f[2].w, wa.z, d.w);
            d.x = fmaf(f[3].x, wa.w, d.x); d.y = fmaf(f[3].y, wa.w, d.y);
            d.z = fmaf(f[3].z, wa.w, d.z); d.w = fmaf(f[3].w, wa.w, d.w);
            d.x = fmaf(f[4].x, wb.x, d.x); d.y = fmaf(f[4].y, wb.x, d.y);
            d.z = fmaf(f[4].z, wb.x, d.z); d.w = fmaf(f[4].w, wb.x, d.w);
            d.x = fmaf(f[5].x, wb.y, d.x); d.y = fmaf(f[5].y, wb.y, d.y);
            d.z = fmaf(f[5].z, wb.y, d.z); d.w = fmaf(f[5].w, wb.y, d.w);
            d.x = fmaf(f[6].x, wb.z, d.x); d.y = fmaf(f[6].y, wb.z, d.y);
            d.z = fmaf(f[6].z, wb.z, d.z); d.w = fmaf(f[6].w, wb.z, d.w);
            d.x = fmaf(f[7].x, wb.w, d.x); d.y = fmaf(f[7].y, wb.w, d.y);
            d.z = fmaf(f[7].z, wb.w, d.z); d.w = fmaf(f[7].w, wb.w, d.w);
            dot[k] = d;
        }
        if (cg + 8 < 64) {
#pragma unroll
            for (int j = 0; j < 8; ++j) f[j] = g[j];
        }
    }

    float ls = 0.0f;
    float* dp = (float*)&dot[0];
    const float* sp = (const float*)&ss;
#pragma unroll
    for (int comp = 0; comp < 4; ++comp) {
        const float sc = TAUINV / fmaxf(sqrtf(sp[comp]), EPS);
        float mx = -1e30f;
#pragma unroll
        for (int k = 0; k < K; ++k) {
            dp[k * 4 + comp] *= sc;
            mx = fmaxf(mx, dp[k * 4 + comp]);
        }
        float se = 0.0f;
#pragma unroll
        for (int k = 0; k < K; ++k) se += expf(dp[k * 4 + comp] - mx);
        const float logZ = mx + logf(se);
        const unsigned m = marr[comp];
        ls += (float)__popc(m) * logZ;
#pragma unroll
        for (int k = 0; k < K; ++k) {
            const int s = ((int)(m << (31 - k))) >> 31;
            ls -= __int_as_float(s & __float_as_int(dp[k * 4 + comp]));
        }
    }

    ls = wave_reduce_f32(ls);
    if ((tid & 63) == 0) atomicAdd(loss_sum, ls);
}

// ---------------- Kernel 4: finalize --------------------------------------
__global__ void k4_final(const float* __restrict__ loss_sum,
                         const unsigned* __restrict__ num_pos,
                         float* __restrict__ out)
{
    out[0] = loss_sum[0] / (float)num_pos[0];
}

// ---------------- launch ---------------------------------------------------
extern "C" void kernel_launch(void* const* d_in, const int* in_sizes, int n_in,
                              void* d_out, int out_size, void* d_ws, size_t ws_size,
                              hipStream_t stream)
{
    const float* feat = (const float*)d_in[0];
    const int*   gt   = (const int*)d_in[1];
    float*       out  = (float*)d_out;

    char* ws = (char*)d_ws;
    unsigned* num_pos  = (unsigned*)(ws + 0);
    float*    loss_sum = (float*)(ws + 4);
    float*    k0p      = (float*)(ws + 256);    // [32][64]
    float*    k0n      = (float*)(ws + 8448);   // [19][64]
    unsigned* pm       = (unsigned*)(ws + 65536);

    hipMemsetAsync(d_ws, 0, 16384, stream);   // zero num_pos/loss_sum/k0p

    k1_proto<<<G1, 1024, 0, stream>>>(feat, gt, pm, k0p, num_pos);
    k2_norm <<<1,  256, 0, stream>>>(k0p, k0n);
    k3_loss <<<NPIX / 1024, 256, 0, stream>>>(feat, gt, pm, k0n, loss_sum);
    k4_final<<<1, 1, 0, stream>>>(loss_sum, num_pos, out);
}

// Round 3
// 541.850 us; speedup vs baseline: 1.0391x; 1.0391x over previous
//
#include <hip/hip_runtime.h>
#include <cstdint>
#include <cstddef>

#define HW    262144          // 512*512
#define C     64
#define K     19
#define NPIX  1048576
#define TAUINV (1.0f / 0.07f)
#define EPS   1e-12f

#define NCHUNK64 (NPIX / 64)  // 16384 chunks of 64 pixels
#define CPB64    (HW / 64)    // 4096 chunks per batch image
#define G1       1024         // k1 blocks: 4096 waves, 4 chunks/wave

// ws layout:
//   +0     unsigned num_pos
//   +4     float    loss_sum
//   +256   float    k0p[32*64]   (8 KB, classes padded to 32)
//   +8448  float    k0n[19*64]
//   +65536 unsigned pm[NPIX]     (4 MB)

typedef __attribute__((ext_vector_type(8))) short bf16x8;
typedef __attribute__((ext_vector_type(4))) float f32x4;

__device__ __forceinline__ float wave_reduce_f32(float v) {
#pragma unroll
    for (int off = 32; off; off >>= 1) v += __shfl_down(v, off);
    return v;
}
__device__ __forceinline__ unsigned wave_reduce_u32(unsigned v) {
#pragma unroll
    for (int off = 32; off; off >>= 1) v += __shfl_down(v, off);
    return v;
}

// RNE f32 -> (bf16 hi, bf16 lo): hi+lo represents f to ~2^-16 relative
__device__ __forceinline__ void split1(float f, short& h, short& l) {
    const unsigned u  = __float_as_uint(f);
    const unsigned hb = (u + 0x7FFFu + ((u >> 16) & 1u)) & 0xFFFF0000u;
    h = (short)(hb >> 16);
    const float lo = f - __uint_as_float(hb);
    const unsigned v = __float_as_uint(lo);
    l = (short)((v + 0x7FFFu + ((v >> 16) & 1u)) >> 16);
}

// ---------------- Kernel 1: MFMA prototypes k0p[32][64] + masks -----------
// 64-px chunks (full-wave coalesced gt/pm). ALL loads for a chunk (19 gt
// dwords + 16 feat float4s = ~17 KB/wave) are issued before any compute so
// memory latency is covered by ILP, not occupancy. launch_bounds(256,3)
// caps VGPR at ~170 (live-set ~145, no spill) -> 3 blocks/CU.
__global__ __launch_bounds__(256, 3) void k1_proto(
    const float* __restrict__ feat, const int* __restrict__ gt,
    unsigned* __restrict__ pm,
    float* __restrict__ k0p, unsigned* __restrict__ num_pos)
{
    __shared__ float red[32 * 64];        // 8 KB block-reduce buffer
    const int tid  = threadIdx.x;
    const int lane = tid & 63;
    const int wv   = tid >> 6;            // 0..3
    const int q    = lane >> 4;           // quad 0..3
    const int n    = lane & 15;           // n/col within fragment
    const int q8   = q << 3;              // this quad's k-offset within K-step

    f32x4 acc[2][4];
#pragma unroll
    for (int mt = 0; mt < 2; ++mt)
#pragma unroll
        for (int nt = 0; nt < 4; ++nt)
            acc[mt][nt] = (f32x4){0.f, 0.f, 0.f, 0.f};
    unsigned npos = 0;

    const int wave_id = blockIdx.x * 4 + wv;
    const int nwaves  = G1 * 4;           // 4096

    for (int chunk = wave_id; chunk < NCHUNK64; chunk += nwaves) {
        const int b   = chunk >> 12;                 // / CPB64
        const int hw0 = (chunk & (CPB64 - 1)) << 6;
        const size_t fbase = (size_t)b * C * HW + hw0;

        // ---- issue ALL gt loads (coalesced 256B each)
        int g[K];
        {
            const int* gp = gt + (size_t)b * K * HW + hw0 + lane;
#pragma unroll
            for (int k = 0; k < K; ++k) g[k] = gp[(size_t)k * HW];
        }

        // ---- issue ALL feat loads: 16 float4s
        //      fx[s*8 + nt*2 + {0,1}] covers channels nt*16+n, pixels s*32+q8..+7
        float4 fx[16];
        {
            const float* fp = feat + fbase + (size_t)n * HW + q8;
#pragma unroll
            for (int s = 0; s < 2; ++s)
#pragma unroll
                for (int nt = 0; nt < 4; ++nt) {
                    const float* p = fp + (size_t)(nt * 16) * HW + s * 32;
                    fx[s * 8 + nt * 2 + 0] = *(const float4*)p;
                    fx[s * 8 + nt * 2 + 1] = *(const float4*)(p + 4);
                }
        }

        // ---- mask from gt (waits only on g; feat loads still in flight)
        unsigned mymask = 0;
#pragma unroll
        for (int k = 0; k < K; ++k)
            mymask |= (g[k] == 1) ? (1u << k) : 0u;
        pm[(size_t)chunk * 64 + lane] = mymask;
        npos += __popc(mymask);

        // ---- two K-steps of 32 pixels each
#pragma unroll
        for (int s = 0; s < 2; ++s) {
            unsigned w8[8];
#pragma unroll
            for (int j = 0; j < 8; ++j) w8[j] = __shfl(mymask, s * 32 + q8 + j);
            bf16x8 a0, a1;
#pragma unroll
            for (int j = 0; j < 8; ++j) {
                a0[j] = (short)(((w8[j] >> n) & 1u) * 0x3F80u);
                a1[j] = (short)(((w8[j] >> (n + 16)) & 1u) * 0x3F80u);
            }

#pragma unroll
            for (int nt = 0; nt < 4; ++nt) {
                const float4 x = fx[s * 8 + nt * 2 + 0];
                const float4 y = fx[s * 8 + nt * 2 + 1];
                bf16x8 bh, bl;
                {
                    short h, l;
                    split1(x.x, h, l); bh[0] = h; bl[0] = l;
                    split1(x.y, h, l); bh[1] = h; bl[1] = l;
                    split1(x.z, h, l); bh[2] = h; bl[2] = l;
                    split1(x.w, h, l); bh[3] = h; bl[3] = l;
                    split1(y.x, h, l); bh[4] = h; bl[4] = l;
                    split1(y.y, h, l); bh[5] = h; bl[5] = l;
                    split1(y.z, h, l); bh[6] = h; bl[6] = l;
                    split1(y.w, h, l); bh[7] = h; bl[7] = l;
                }
                acc[0][nt] = __builtin_amdgcn_mfma_f32_16x16x32_bf16(a0, bh, acc[0][nt], 0, 0, 0);
                acc[0][nt] = __builtin_amdgcn_mfma_f32_16x16x32_bf16(a0, bl, acc[0][nt], 0, 0, 0);
                acc[1][nt] = __builtin_amdgcn_mfma_f32_16x16x32_bf16(a1, bh, acc[1][nt], 0, 0, 0);
                acc[1][nt] = __builtin_amdgcn_mfma_f32_16x16x32_bf16(a1, bl, acc[1][nt], 0, 0, 0);
            }
        }
    }

    // ---- block reduce (D layout: class = mt*16 + q*4 + r, ch = nt*16 + n)
    for (int w = 0; w < 4; ++w) {
        if (wv == w) {
#pragma unroll
            for (int mt = 0; mt < 2; ++mt)
#pragma unroll
                for (int nt = 0; nt < 4; ++nt)
#pragma unroll
                    for (int r = 0; r < 4; ++r) {
                        const int idx = (mt * 16 + q * 4 + r) * 64 + nt * 16 + n;
                        if (w == 0) red[idx]  = acc[mt][nt][r];
                        else        red[idx] += acc[mt][nt][r];
                    }
        }
        __syncthreads();
    }
    // only the 19 real classes (rows 19..31 are identically zero)
    for (int i = tid; i < K * 64; i += 256)
        atomicAdd(&k0p[i], red[i]);

    const unsigned np = wave_reduce_u32(npos);
    if (lane == 0) atomicAdd(num_pos, np);
}

// ---------------- Kernel 2: normalize prototypes --------------------------
__global__ __launch_bounds__(256) void k2_norm(
    const float* __restrict__ k0p, float* __restrict__ k0n)
{
    __shared__ float rn[K];
    const int tid  = threadIdx.x;
    const int lane = tid & 63;
    const int wv   = tid >> 6;
    for (int cls = wv; cls < K; cls += 4) {
        const float v = k0p[cls * 64 + lane];
        const float s = wave_reduce_f32(v * v);
        if (lane == 0) rn[cls] = 1.0f / fmaxf(sqrtf(s), EPS);
    }
    __syncthreads();
    for (int i = tid; i < K * 64; i += 256) k0n[i] = k0p[i] * rn[i >> 6];
}

// ---------------- Kernel 3: logits + log-softmax + masked NLL -------------
__global__ __launch_bounds__(256) void k3_loss(
    const float* __restrict__ feat, const int* __restrict__ gt,
    const unsigned* __restrict__ pm, const float* __restrict__ k0n,
    float* __restrict__ loss_sum)
{
    __shared__ __align__(16) float w[K * 64];
    const int tid = threadIdx.x;
    for (int i = tid; i < K * 64; i += 256) w[i] = k0n[i];
    __syncthreads();

    const int px0 = (blockIdx.x * 256 + tid) << 2;
    const int b   = px0 >> 18;
    const int hw  = px0 & (HW - 1);
    const float* fb = feat + (size_t)b * C * HW + hw;

    unsigned marr[4];
    {
        const uint4 mv = *(const uint4*)(pm + px0);
        marr[0] = mv.x; marr[1] = mv.y; marr[2] = mv.z; marr[3] = mv.w;
    }

    float4 dot[K];
#pragma unroll
    for (int k = 0; k < K; ++k) dot[k] = make_float4(0.f, 0.f, 0.f, 0.f);
    float4 ss = make_float4(0.f, 0.f, 0.f, 0.f);

    float4 f[8];
#pragma unroll
    for (int j = 0; j < 8; ++j)
        f[j] = *(const float4*)(fb + (size_t)j * HW);

#pragma unroll
    for (int cg = 0; cg < 64; cg += 8) {
        float4 g[8];
        if (cg + 8 < 64) {
#pragma unroll
            for (int j = 0; j < 8; ++j)
                g[j] = *(const float4*)(fb + (size_t)(cg + 8 + j) * HW);
        }
#pragma unroll
        for (int j = 0; j < 8; ++j) {
            const float4 fv = f[j];
            ss.x = fmaf(fv.x, fv.x, ss.x); ss.y = fmaf(fv.y, fv.y, ss.y);
            ss.z = fmaf(fv.z, fv.z, ss.z); ss.w = fmaf(fv.w, fv.w, ss.w);
        }
#pragma unroll
        for (int k = 0; k < K; ++k) {
            const float4 wa = *(const float4*)&w[k * 64 + cg];
            const float4 wb = *(const float4*)&w[k * 64 + cg + 4];
            float4 d = dot[k];
            d.x = fmaf(f[0].x, wa.x, d.x); d.y = fmaf(f[0].y, wa.x, d.y);
            d.z = fmaf(f[0].z, wa.x, d.z); d.w = fmaf(f[0].w, wa.x, d.w);
            d.x = fmaf(f[1].x, wa.y, d.x); d.y = fmaf(f[1].y, wa.y, d.y);
            d.z = fmaf(f[1].z, wa.y, d.z); d.w = fmaf(f[1].w, wa.y, d.w);
            d.x = fmaf(f[2].x, wa.z, d.x); d.y = fmaf(f[2].y, wa.z, d.y);
            d.z = fmaf(f[2].z, wa.z, d.z); d.w = fmaf(f[2].w, wa.z, d.w);
            d.x = fmaf(f[3].x, wa.w, d.x); d.y = fmaf(f[3].y, wa.w, d.y);
            d.z = fmaf(f[3].z, wa.w, d.z); d.w = fmaf(f[3].w, wa.w, d.w);
            d.x = fmaf(f[4].x, wb.x, d.x); d.y = fmaf(f[4].y, wb.x, d.y);
            d.z = fmaf(f[4].z, wb.x, d.z); d.w = fmaf(f[4].w, wb.x, d.w);
            d.x = fmaf(f[5].x, wb.y, d.x); d.y = fmaf(f[5].y, wb.y, d.y);
            d.z = fmaf(f[5].z, wb.y, d.z); d.w = fmaf(f[5].w, wb.y, d.w);
            d.x = fmaf(f[6].x, wb.z, d.x); d.y = fmaf(f[6].y, wb.z, d.y);
            d.z = fmaf(f[6].z, wb.z, d.z); d.w = fmaf(f[6].w, wb.z, d.w);
            d.x = fmaf(f[7].x, wb.w, d.x); d.y = fmaf(f[7].y, wb.w, d.y);
            d.z = fmaf(f[7].z, wb.w, d.z); d.w = fmaf(f[7].w, wb.w, d.w);
            dot[k] = d;
        }
        if (cg + 8 < 64) {
#pragma unroll
            for (int j = 0; j < 8; ++j) f[j] = g[j];
        }
    }

    float ls = 0.0f;
    float* dp = (float*)&dot[0];
    const float* sp = (const float*)&ss;
#pragma unroll
    for (int comp = 0; comp < 4; ++comp) {
        const float sc = TAUINV / fmaxf(sqrtf(sp[comp]), EPS);
        float mx = -1e30f;
#pragma unroll
        for (int k = 0; k < K; ++k) {
            dp[k * 4 + comp] *= sc;
            mx = fmaxf(mx, dp[k * 4 + comp]);
        }
        float se = 0.0f;
#pragma unroll
        for (int k = 0; k < K; ++k) se += expf(dp[k * 4 + comp] - mx);
        const float logZ = mx + logf(se);
        const unsigned m = marr[comp];
        ls += (float)__popc(m) * logZ;
#pragma unroll
        for (int k = 0; k < K; ++k) {
            const int s = ((int)(m << (31 - k))) >> 31;
            ls -= __int_as_float(s & __float_as_int(dp[k * 4 + comp]));
        }
    }

    ls = wave_reduce_f32(ls);
    if ((tid & 63) == 0) atomicAdd(loss_sum, ls);
}

// ---------------- Kernel 4: finalize --------------------------------------
__global__ void k4_final(const float* __restrict__ loss_sum,
                         const unsigned* __restrict__ num_pos,
                         float* __restrict__ out)
{
    out[0] = loss_sum[0] / (float)num_pos[0];
}

// ---------------- launch ---------------------------------------------------
extern "C" void kernel_launch(void* const* d_in, const int* in_sizes, int n_in,
                              void* d_out, int out_size, void* d_ws, size_t ws_size,
                              hipStream_t stream)
{
    const float* feat = (const float*)d_in[0];
    const int*   gt   = (const int*)d_in[1];
    float*       out  = (float*)d_out;

    char* ws = (char*)d_ws;
    unsigned* num_pos  = (unsigned*)(ws + 0);
    float*    loss_sum = (float*)(ws + 4);
    float*    k0p      = (float*)(ws + 256);    // [32][64]
    float*    k0n      = (float*)(ws + 8448);   // [19][64]
    unsigned* pm       = (unsigned*)(ws + 65536);

    hipMemsetAsync(d_ws, 0, 16384, stream);   // zero num_pos/loss_sum/k0p

    k1_proto<<<G1, 256, 0, stream>>>(feat, gt, pm, k0p, num_pos);
    k2_norm <<<1,  256, 0, stream>>>(k0p, k0n);
    k3_loss <<<NPIX / 1024, 256, 0, stream>>>(feat, gt, pm, k0n, loss_sum);
    k4_final<<<1, 1, 0, stream>>>(loss_sum, num_pos, out);
}

// Round 4
// 533.139 us; speedup vs baseline: 1.0561x; 1.0163x over previous
//
#include <hip/hip_runtime.h>
#include <cstdint>
#include <cstddef>

#define HW    262144          // 512*512
#define C     64
#define K     19
#define NPIX  1048576
#define TAUINV (1.0f / 0.07f)
#define EPS   1e-12f

#define TPX   128                    // pixels per k1 tile
#define NTILE (NPIX / TPX)           // 8192
#define TPB   (HW / TPX)             // 2048 tiles per image
#define G1    512                    // k1 blocks, 16 tiles each, all resident (3/CU cap)
#define TILES_PER_BLOCK (NTILE / G1) // 16

// ws layout:
//   +0     unsigned num_pos
//   +4     float    loss_sum
//   +256   float    k0p[32*64]   (8 KB, classes padded to 32)
//   +8448  float    k0n[19*64]
//   +65536 unsigned pm[NPIX]     (4 MB)

typedef __attribute__((ext_vector_type(8))) short bf16x8;
typedef __attribute__((ext_vector_type(4))) float f32x4;

__device__ __forceinline__ float wave_reduce_f32(float v) {
#pragma unroll
    for (int off = 32; off; off >>= 1) v += __shfl_down(v, off);
    return v;
}
__device__ __forceinline__ unsigned wave_reduce_u32(unsigned v) {
#pragma unroll
    for (int off = 32; off; off >>= 1) v += __shfl_down(v, off);
    return v;
}

// RNE f32 -> (bf16 hi, bf16 lo): hi+lo represents f to ~2^-16 relative
__device__ __forceinline__ void split1(float f, short& h, short& l) {
    const unsigned u  = __float_as_uint(f);
    const unsigned hb = (u + 0x7FFFu + ((u >> 16) & 1u)) & 0xFFFF0000u;
    h = (short)(hb >> 16);
    const float lo = f - __uint_as_float(hb);
    const unsigned v = __float_as_uint(lo);
    l = (short)((v + 0x7FFFu + ((v >> 16) & 1u)) >> 16);
}

// ---------------- Kernel 1: LDS-tiled MFMA prototypes ---------------------
// Per block: 16 tiles of [64 ch][128 px]. Staging reads are CONTIGUOUS
// 512B-per-half-wave row runs (k3's proven-roofline pattern) into a linear
// LDS tile; MFMA fragments then come from ds_read_b128, so the 16-row
// fragment scatter happens in LDS, not at HBM. Wave wv owns K-step s=wv
// (px wv*32..wv*32+31). Arithmetic identical to previous k1.
__global__ __launch_bounds__(256, 3) void k1_proto(
    const float* __restrict__ feat, const int* __restrict__ gt,
    unsigned* __restrict__ pm,
    float* __restrict__ k0p, unsigned* __restrict__ num_pos)
{
    __shared__ __align__(16) float ftile[64][TPX];   // 32 KB
    __shared__ __align__(16) int   gtile[20][TPX];   // 10 KB (row 19 = pad)
    __shared__ float red[32 * 64];                   // 8 KB block-reduce
    __shared__ unsigned nps[4];

    const int tid  = threadIdx.x;
    const int lane = tid & 63;
    const int wv   = tid >> 6;            // 0..3, also the K-step this wave owns
    const int q    = lane >> 4;           // quad 0..3
    const int n    = lane & 15;           // n/col within fragment
    const int q8   = q << 3;              // quad's k-offset within K-step
    const int half = lane >> 5;           // 0/1: which row of a 2-row stage instr
    const int i2   = lane & 31;           // 16B-block within a 512B row run

    f32x4 acc[2][4];
#pragma unroll
    for (int mt = 0; mt < 2; ++mt)
#pragma unroll
        for (int nt = 0; nt < 4; ++nt)
            acc[mt][nt] = (f32x4){0.f, 0.f, 0.f, 0.f};
    unsigned npos = 0;

    const int T0 = blockIdx.x * TILES_PER_BLOCK;
    const int b  = T0 >> 11;              // blocks never straddle images (2048/16=128)
    const float* fB = feat + (size_t)b * C * HW;
    const int*   gB = gt   + (size_t)b * K * HW;

    for (int t = 0; t < TILES_PER_BLOCK; ++t) {
        const int T   = T0 + t;
        const int px0 = (T & (TPB - 1)) << 7;   // *128

        // ---- stage feat: 32 instrs (2 rows each), wave wv does i=wv,wv+4,...
        //      each half-wave reads 512 B contiguous from one channel row.
        float4 fr[8];
#pragma unroll
        for (int ii = 0; ii < 8; ++ii) {
            const int row = 2 * (wv + 4 * ii) + half;
            fr[ii] = *(const float4*)(fB + (size_t)row * HW + px0 + i2 * 4);
        }
        // ---- stage gt: 10 instrs (2 rows each; last instr re-reads row 18)
        int4 gr[3];
        const int ngt = (wv < 2) ? 3 : 2;       // waves 0,1: j=wv,wv+4,wv+8; waves 2,3: j=wv,wv+4
#pragma unroll
        for (int jj = 0; jj < 3; ++jj) {
            if (jj < ngt) {
                const int j   = wv + 4 * jj;
                const int row = 2 * j + half;
                const int srow = row > 18 ? 18 : row;   // OOB guard (pad row)
                gr[jj] = *(const int4*)(gB + (size_t)srow * HW + px0 + i2 * 4);
            }
        }
        // ---- LDS writes
#pragma unroll
        for (int ii = 0; ii < 8; ++ii) {
            const int row = 2 * (wv + 4 * ii) + half;
            *(float4*)&ftile[row][i2 * 4] = fr[ii];
        }
#pragma unroll
        for (int jj = 0; jj < 3; ++jj) {
            if (jj < ngt) {
                const int row = 2 * (wv + 4 * jj) + half;
                *(int4*)&gtile[row][i2 * 4] = gr[jj];
            }
        }
        __syncthreads();

        // ---- packed mask for this wave's 32-px slice (lanes 32-63 duplicate)
        unsigned mymask = 0;
        {
            const int px = wv * 32 + (lane & 31);
#pragma unroll
            for (int k = 0; k < K; ++k)
                mymask |= (gtile[k][px] == 1) ? (1u << k) : 0u;
        }
        if (lane < 32) {
            pm[(size_t)T * TPX + wv * 32 + lane] = mymask;
            npos += __popc(mymask);
        }

        // ---- A fragments: class rows m=n / n+16, k-slot j -> px wv*32+q8+j
        unsigned w8[8];
#pragma unroll
        for (int j = 0; j < 8; ++j) w8[j] = __shfl(mymask, q8 + j);
        bf16x8 a0, a1;
#pragma unroll
        for (int j = 0; j < 8; ++j) {
            a0[j] = (short)(((w8[j] >> n) & 1u) * 0x3F80u);
            a1[j] = (short)(((w8[j] >> (n + 16)) & 1u) * 0x3F80u);
        }

        // ---- B fragments from LDS + MFMA, per 16-channel N-tile
#pragma unroll
        for (int nt = 0; nt < 4; ++nt) {
            const float* p = &ftile[nt * 16 + n][wv * 32 + q8];
            const float4 x = *(const float4*)p;
            const float4 y = *(const float4*)(p + 4);
            bf16x8 bh, bl;
            {
                short h, l;
                split1(x.x, h, l); bh[0] = h; bl[0] = l;
                split1(x.y, h, l); bh[1] = h; bl[1] = l;
                split1(x.z, h, l); bh[2] = h; bl[2] = l;
                split1(x.w, h, l); bh[3] = h; bl[3] = l;
                split1(y.x, h, l); bh[4] = h; bl[4] = l;
                split1(y.y, h, l); bh[5] = h; bl[5] = l;
                split1(y.z, h, l); bh[6] = h; bl[6] = l;
                split1(y.w, h, l); bh[7] = h; bl[7] = l;
            }
            acc[0][nt] = __builtin_amdgcn_mfma_f32_16x16x32_bf16(a0, bh, acc[0][nt], 0, 0, 0);
            acc[0][nt] = __builtin_amdgcn_mfma_f32_16x16x32_bf16(a0, bl, acc[0][nt], 0, 0, 0);
            acc[1][nt] = __builtin_amdgcn_mfma_f32_16x16x32_bf16(a1, bh, acc[1][nt], 0, 0, 0);
            acc[1][nt] = __builtin_amdgcn_mfma_f32_16x16x32_bf16(a1, bl, acc[1][nt], 0, 0, 0);
        }
        __syncthreads();   // protect LDS before next tile's staging
    }

    // ---- per-block num_pos reduce (1 global atomic per block, was 16)
    {
        const unsigned np = wave_reduce_u32(npos);
        if (lane == 0) nps[wv] = np;
    }

    // ---- block reduce (D layout: class = mt*16 + q*4 + r, ch = nt*16 + n)
    for (int w = 0; w < 4; ++w) {
        if (wv == w) {
#pragma unroll
            for (int mt = 0; mt < 2; ++mt)
#pragma unroll
                for (int nt = 0; nt < 4; ++nt)
#pragma unroll
                    for (int r = 0; r < 4; ++r) {
                        const int idx = (mt * 16 + q * 4 + r) * 64 + nt * 16 + n;
                        if (w == 0) red[idx]  = acc[mt][nt][r];
                        else        red[idx] += acc[mt][nt][r];
                    }
        }
        __syncthreads();
    }
    // only the 19 real classes (rows 19..31 are identically zero)
    for (int i = tid; i < K * 64; i += 256)
        atomicAdd(&k0p[i], red[i]);
    if (tid == 0)
        atomicAdd(num_pos, nps[0] + nps[1] + nps[2] + nps[3]);
}

// ---------------- Kernel 2: normalize prototypes --------------------------
__global__ __launch_bounds__(256) void k2_norm(
    const float* __restrict__ k0p, float* __restrict__ k0n)
{
    __shared__ float rn[K];
    const int tid  = threadIdx.x;
    const int lane = tid & 63;
    const int wv   = tid >> 6;
    for (int cls = wv; cls < K; cls += 4) {
        const float v = k0p[cls * 64 + lane];
        const float s = wave_reduce_f32(v * v);
        if (lane == 0) rn[cls] = 1.0f / fmaxf(sqrtf(s), EPS);
    }
    __syncthreads();
    for (int i = tid; i < K * 64; i += 256) k0n[i] = k0p[i] * rn[i >> 6];
}

// ---------------- Kernel 3: logits + log-softmax + masked NLL -------------
__global__ __launch_bounds__(256) void k3_loss(
    const float* __restrict__ feat, const int* __restrict__ gt,
    const unsigned* __restrict__ pm, const float* __restrict__ k0n,
    float* __restrict__ loss_sum)
{
    __shared__ __align__(16) float w[K * 64];
    const int tid = threadIdx.x;
    for (int i = tid; i < K * 64; i += 256) w[i] = k0n[i];
    __syncthreads();

    const int px0 = (blockIdx.x * 256 + tid) << 2;
    const int b   = px0 >> 18;
    const int hw  = px0 & (HW - 1);
    const float* fb = feat + (size_t)b * C * HW + hw;

    unsigned marr[4];
    {
        const uint4 mv = *(const uint4*)(pm + px0);
        marr[0] = mv.x; marr[1] = mv.y; marr[2] = mv.z; marr[3] = mv.w;
    }

    float4 dot[K];
#pragma unroll
    for (int k = 0; k < K; ++k) dot[k] = make_float4(0.f, 0.f, 0.f, 0.f);
    float4 ss = make_float4(0.f, 0.f, 0.f, 0.f);

    float4 f[8];
#pragma unroll
    for (int j = 0; j < 8; ++j)
        f[j] = *(const float4*)(fb + (size_t)j * HW);

#pragma unroll
    for (int cg = 0; cg < 64; cg += 8) {
        float4 g[8];
        if (cg + 8 < 64) {
#pragma unroll
            for (int j = 0; j < 8; ++j)
                g[j] = *(const float4*)(fb + (size_t)(cg + 8 + j) * HW);
        }
#pragma unroll
        for (int j = 0; j < 8; ++j) {
            const float4 fv = f[j];
            ss.x = fmaf(fv.x, fv.x, ss.x); ss.y = fmaf(fv.y, fv.y, ss.y);
            ss.z = fmaf(fv.z, fv.z, ss.z); ss.w = fmaf(fv.w, fv.w, ss.w);
        }
#pragma unroll
        for (int k = 0; k < K; ++k) {
            const float4 wa = *(const float4*)&w[k * 64 + cg];
            const float4 wb = *(const float4*)&w[k * 64 + cg + 4];
            float4 d = dot[k];
            d.x = fmaf(f[0].x, wa.x, d.x); d.y = fmaf(f[0].y, wa.x, d.y);
            d.z = fmaf(f[0].z, wa.x, d.z); d.w = fmaf(f[0].w, wa.x, d.w);
            d.x = fmaf(f[1].x, wa.y, d.x); d.y = fmaf(f[1].y, wa.y, d.y);
            d.z = fmaf(f[1].z, wa.y, d.z); d.w = fmaf(f[1].w, wa.y, d.w);
            d.x = fmaf(f[2].x, wa.z, d.x); d.y = fmaf(f[2].y, wa.z, d.y);
            d.z = fmaf(f[2].z, wa.z, d.z); d.w = fmaf(f[2].w, wa.z, d.w);
            d.x = fmaf(f[3].x, wa.w, d.x); d.y = fmaf(f[3].y, wa.w, d.y);
            d.z = fmaf(f[3].z, wa.w, d.z); d.w = fmaf(f[3].w, wa.w, d.w);
            d.x = fmaf(f[4].x, wb.x, d.x); d.y = fmaf(f[4].y, wb.x, d.y);
            d.z = fmaf(f[4].z, wb.x, d.z); d.w = fmaf(f[4].w, wb.x, d.w);
            d.x = fmaf(f[5].x, wb.y, d.x); d.y = fmaf(f[5].y, wb.y, d.y);
            d.z = fmaf(f[5].z, wb.y, d.z); d.w = fmaf(f[5].w, wb.y, d.w);
            d.x = fmaf(f[6].x, wb.z, d.x); d.y = fmaf(f[6].y, wb.z, d.y);
            d.z = fmaf(f[6].z, wb.z, d.z); d.w = fmaf(f[6].w, wb.z, d.w);
            d.x = fmaf(f[7].x, wb.w, d.x); d.y = fmaf(f[7].y, wb.w, d.y);
            d.z = fmaf(f[7].z, wb.w, d.z); d.w = fmaf(f[7].w, wb.w, d.w);
            dot[k] = d;
        }
        if (cg + 8 < 64) {
#pragma unroll
            for (int j = 0; j < 8; ++j) f[j] = g[j];
        }
    }

    float ls = 0.0f;
    float* dp = (float*)&dot[0];
    const float* sp = (const float*)&ss;
#pragma unroll
    for (int comp = 0; comp < 4; ++comp) {
        const float sc = TAUINV / fmaxf(sqrtf(sp[comp]), EPS);
        float mx = -1e30f;
#pragma unroll
        for (int k = 0; k < K; ++k) {
            dp[k * 4 + comp] *= sc;
            mx = fmaxf(mx, dp[k * 4 + comp]);
        }
        float se = 0.0f;
#pragma unroll
        for (int k = 0; k < K; ++k) se += expf(dp[k * 4 + comp] - mx);
        const float logZ = mx + logf(se);
        const unsigned m = marr[comp];
        ls += (float)__popc(m) * logZ;
#pragma unroll
        for (int k = 0; k < K; ++k) {
            const int s = ((int)(m << (31 - k))) >> 31;
            ls -= __int_as_float(s & __float_as_int(dp[k * 4 + comp]));
        }
    }

    ls = wave_reduce_f32(ls);
    if ((tid & 63) == 0) atomicAdd(loss_sum, ls);
}

// ---------------- Kernel 4: finalize --------------------------------------
__global__ void k4_final(const float* __restrict__ loss_sum,
                         const unsigned* __restrict__ num_pos,
                         float* __restrict__ out)
{
    out[0] = loss_sum[0] / (float)num_pos[0];
}

// ---------------- launch ---------------------------------------------------
extern "C" void kernel_launch(void* const* d_in, const int* in_sizes, int n_in,
                              void* d_out, int out_size, void* d_ws, size_t ws_size,
                              hipStream_t stream)
{
    const float* feat = (const float*)d_in[0];
    const int*   gt   = (const int*)d_in[1];
    float*       out  = (float*)d_out;

    char* ws = (char*)d_ws;
    unsigned* num_pos  = (unsigned*)(ws + 0);
    float*    loss_sum = (float*)(ws + 4);
    float*    k0p      = (float*)(ws + 256);    // [32][64]
    float*    k0n      = (float*)(ws + 8448);   // [19][64]
    unsigned* pm       = (unsigned*)(ws + 65536);

    hipMemsetAsync(d_ws, 0, 16384, stream);   // zero num_pos/loss_sum/k0p

    k1_proto<<<G1, 256, 0, stream>>>(feat, gt, pm, k0p, num_pos);
    k2_norm <<<1,  256, 0, stream>>>(k0p, k0n);
    k3_loss <<<NPIX / 1024, 256, 0, stream>>>(feat, gt, pm, k0n, loss_sum);
    k4_final<<<1, 1, 0, stream>>>(loss_sum, num_pos, out);
}

// Round 5
// 529.467 us; speedup vs baseline: 1.0634x; 1.0069x over previous
//
#include <hip/hip_runtime.h>
#include <cstdint>
#include <cstddef>

#define HW    262144          // 512*512
#define C     64
#define K     19
#define NPIX  1048576
#define TAUINV (1.0f / 0.07f)
#define EPS   1e-12f

#define TPX   128                    // pixels per k1 tile
#define NTILE (NPIX / TPX)           // 8192
#define TPB   (HW / TPX)             // 2048 tiles per image
#define G1    512                    // k1 blocks, 16 tiles each
#define TILES_PER_BLOCK (NTILE / G1) // 16

// ws layout:
//   +0     unsigned num_pos
//   +4     float    loss_sum
//   +256   float    k0p[32*64]   (8 KB, classes padded to 32)
//   +8448  float    k0n[19*64]
//   +65536 unsigned pm[NPIX]     (4 MB)

typedef __attribute__((ext_vector_type(8))) short bf16x8;
typedef __attribute__((ext_vector_type(4))) float f32x4;

__device__ __forceinline__ float wave_reduce_f32(float v) {
#pragma unroll
    for (int off = 32; off; off >>= 1) v += __shfl_down(v, off);
    return v;
}
__device__ __forceinline__ unsigned wave_reduce_u32(unsigned v) {
#pragma unroll
    for (int off = 32; off; off >>= 1) v += __shfl_down(v, off);
    return v;
}

// RNE f32 -> (bf16 hi, bf16 lo): hi+lo represents f to ~2^-16 relative
__device__ __forceinline__ void split1(float f, short& h, short& l) {
    const unsigned u  = __float_as_uint(f);
    const unsigned hb = (u + 0x7FFFu + ((u >> 16) & 1u)) & 0xFFFF0000u;
    h = (short)(hb >> 16);
    const float lo = f - __uint_as_float(hb);
    const unsigned v = __float_as_uint(lo);
    l = (short)((v + 0x7FFFu + ((v >> 16) & 1u)) >> 16);
}

// ---------------- Kernel 1: LDS-tiled MFMA prototypes ---------------------
// Per block: 16 tiles of [64 ch][128 px]. Staging reads are CONTIGUOUS
// 512B-per-half-wave row runs into a linear LDS tile; MFMA fragments then
// come from ds_read_b128, so the fragment scatter happens in LDS, not HBM.
__global__ __launch_bounds__(256, 3) void k1_proto(
    const float* __restrict__ feat, const int* __restrict__ gt,
    unsigned* __restrict__ pm,
    float* __restrict__ k0p, unsigned* __restrict__ num_pos)
{
    __shared__ __align__(16) float ftile[64][TPX];   // 32 KB
    __shared__ __align__(16) int   gtile[20][TPX];   // 10 KB (row 19 = pad)
    __shared__ float red[32 * 64];                   // 8 KB block-reduce
    __shared__ unsigned nps[4];

    const int tid  = threadIdx.x;
    const int lane = tid & 63;
    const int wv   = tid >> 6;            // 0..3, also the K-step this wave owns
    const int q    = lane >> 4;           // quad 0..3
    const int n    = lane & 15;           // n/col within fragment
    const int q8   = q << 3;              // quad's k-offset within K-step
    const int half = lane >> 5;           // 0/1: which row of a 2-row stage instr
    const int i2   = lane & 31;           // 16B-block within a 512B row run

    f32x4 acc[2][4];
#pragma unroll
    for (int mt = 0; mt < 2; ++mt)
#pragma unroll
        for (int nt = 0; nt < 4; ++nt)
            acc[mt][nt] = (f32x4){0.f, 0.f, 0.f, 0.f};
    unsigned npos = 0;

    const int T0 = blockIdx.x * TILES_PER_BLOCK;
    const int b  = T0 >> 11;              // blocks never straddle images (2048/16=128)
    const float* fB = feat + (size_t)b * C * HW;
    const int*   gB = gt   + (size_t)b * K * HW;

    for (int t = 0; t < TILES_PER_BLOCK; ++t) {
        const int T   = T0 + t;
        const int px0 = (T & (TPB - 1)) << 7;   // *128

        // ---- stage feat: 32 instrs (2 rows each), wave wv does i=wv,wv+4,...
        float4 fr[8];
#pragma unroll
        for (int ii = 0; ii < 8; ++ii) {
            const int row = 2 * (wv + 4 * ii) + half;
            fr[ii] = *(const float4*)(fB + (size_t)row * HW + px0 + i2 * 4);
        }
        // ---- stage gt: 10 instrs (2 rows each; tail re-reads row 18)
        int4 gr[3];
        const int ngt = (wv < 2) ? 3 : 2;
#pragma unroll
        for (int jj = 0; jj < 3; ++jj) {
            if (jj < ngt) {
                const int j   = wv + 4 * jj;
                const int row = 2 * j + half;
                const int srow = row > 18 ? 18 : row;   // OOB guard (pad row)
                gr[jj] = *(const int4*)(gB + (size_t)srow * HW + px0 + i2 * 4);
            }
        }
        // ---- LDS writes
#pragma unroll
        for (int ii = 0; ii < 8; ++ii) {
            const int row = 2 * (wv + 4 * ii) + half;
            *(float4*)&ftile[row][i2 * 4] = fr[ii];
        }
#pragma unroll
        for (int jj = 0; jj < 3; ++jj) {
            if (jj < ngt) {
                const int row = 2 * (wv + 4 * jj) + half;
                *(int4*)&gtile[row][i2 * 4] = gr[jj];
            }
        }
        __syncthreads();

        // ---- packed mask for this wave's 32-px slice (lanes 32-63 duplicate)
        unsigned mymask = 0;
        {
            const int px = wv * 32 + (lane & 31);
#pragma unroll
            for (int k = 0; k < K; ++k)
                mymask |= (gtile[k][px] == 1) ? (1u << k) : 0u;
        }
        if (lane < 32) {
            pm[(size_t)T * TPX + wv * 32 + lane] = mymask;
            npos += __popc(mymask);
        }

        // ---- A fragments: class rows m=n / n+16, k-slot j -> px wv*32+q8+j
        unsigned w8[8];
#pragma unroll
        for (int j = 0; j < 8; ++j) w8[j] = __shfl(mymask, q8 + j);
        bf16x8 a0, a1;
#pragma unroll
        for (int j = 0; j < 8; ++j) {
            a0[j] = (short)(((w8[j] >> n) & 1u) * 0x3F80u);
            a1[j] = (short)(((w8[j] >> (n + 16)) & 1u) * 0x3F80u);
        }

        // ---- B fragments from LDS + MFMA, per 16-channel N-tile
#pragma unroll
        for (int nt = 0; nt < 4; ++nt) {
            const float* p = &ftile[nt * 16 + n][wv * 32 + q8];
            const float4 x = *(const float4*)p;
            const float4 y = *(const float4*)(p + 4);
            bf16x8 bh, bl;
            {
                short h, l;
                split1(x.x, h, l); bh[0] = h; bl[0] = l;
                split1(x.y, h, l); bh[1] = h; bl[1] = l;
                split1(x.z, h, l); bh[2] = h; bl[2] = l;
                split1(x.w, h, l); bh[3] = h; bl[3] = l;
                split1(y.x, h, l); bh[4] = h; bl[4] = l;
                split1(y.y, h, l); bh[5] = h; bl[5] = l;
                split1(y.z, h, l); bh[6] = h; bl[6] = l;
                split1(y.w, h, l); bh[7] = h; bl[7] = l;
            }
            acc[0][nt] = __builtin_amdgcn_mfma_f32_16x16x32_bf16(a0, bh, acc[0][nt], 0, 0, 0);
            acc[0][nt] = __builtin_amdgcn_mfma_f32_16x16x32_bf16(a0, bl, acc[0][nt], 0, 0, 0);
            acc[1][nt] = __builtin_amdgcn_mfma_f32_16x16x32_bf16(a1, bh, acc[1][nt], 0, 0, 0);
            acc[1][nt] = __builtin_amdgcn_mfma_f32_16x16x32_bf16(a1, bl, acc[1][nt], 0, 0, 0);
        }
        __syncthreads();   // protect LDS before next tile's staging
    }

    // ---- per-block num_pos reduce (1 global atomic per block)
    {
        const unsigned np = wave_reduce_u32(npos);
        if (lane == 0) nps[wv] = np;
    }

    // ---- block reduce (D layout: class = mt*16 + q*4 + r, ch = nt*16 + n)
    for (int w = 0; w < 4; ++w) {
        if (wv == w) {
#pragma unroll
            for (int mt = 0; mt < 2; ++mt)
#pragma unroll
                for (int nt = 0; nt < 4; ++nt)
#pragma unroll
                    for (int r = 0; r < 4; ++r) {
                        const int idx = (mt * 16 + q * 4 + r) * 64 + nt * 16 + n;
                        if (w == 0) red[idx]  = acc[mt][nt][r];
                        else        red[idx] += acc[mt][nt][r];
                    }
        }
        __syncthreads();
    }
    // only the 19 real classes (rows 19..31 are identically zero)
    for (int i = tid; i < K * 64; i += 256)
        atomicAdd(&k0p[i], red[i]);
    if (tid == 0)
        atomicAdd(num_pos, nps[0] + nps[1] + nps[2] + nps[3]);
}

// ---------------- Kernel 2: normalize prototypes --------------------------
__global__ __launch_bounds__(256) void k2_norm(
    const float* __restrict__ k0p, float* __restrict__ k0n)
{
    __shared__ float rn[K];
    const int tid  = threadIdx.x;
    const int lane = tid & 63;
    const int wv   = tid >> 6;
    for (int cls = wv; cls < K; cls += 4) {
        const float v = k0p[cls * 64 + lane];
        const float s = wave_reduce_f32(v * v);
        if (lane == 0) rn[cls] = 1.0f / fmaxf(sqrtf(s), EPS);
    }
    __syncthreads();
    for (int i = tid; i < K * 64; i += 256) k0n[i] = k0p[i] * rn[i >> 6];
}

// ---------------- Kernel 3: logits + log-softmax + masked NLL -------------
// launch_bounds(256, 2): VGPR cap 256 so dot[19] (76 VGPRs) + the 16-deep
// f/g load pipeline stay IN REGISTERS. Default heuristic allocated 64 VGPRs
// and spilled the accumulators to scratch -> 160us latency-bound (R4 PMC).
__global__ __launch_bounds__(256, 2) void k3_loss(
    const float* __restrict__ feat, const int* __restrict__ gt,
    const unsigned* __restrict__ pm, const float* __restrict__ k0n,
    float* __restrict__ loss_sum)
{
    __shared__ __align__(16) float w[K * 64];
    const int tid = threadIdx.x;
    for (int i = tid; i < K * 64; i += 256) w[i] = k0n[i];
    __syncthreads();

    const int px0 = (blockIdx.x * 256 + tid) << 2;
    const int b   = px0 >> 18;
    const int hw  = px0 & (HW - 1);
    const float* fb = feat + (size_t)b * C * HW + hw;

    unsigned marr[4];
    {
        const uint4 mv = *(const uint4*)(pm + px0);
        marr[0] = mv.x; marr[1] = mv.y; marr[2] = mv.z; marr[3] = mv.w;
    }

    float4 dot[K];
#pragma unroll
    for (int k = 0; k < K; ++k) dot[k] = make_float4(0.f, 0.f, 0.f, 0.f);
    float4 ss = make_float4(0.f, 0.f, 0.f, 0.f);

    float4 f[8];
#pragma unroll
    for (int j = 0; j < 8; ++j)
        f[j] = *(const float4*)(fb + (size_t)j * HW);

#pragma unroll
    for (int cg = 0; cg < 64; cg += 8) {
        float4 g[8];
        if (cg + 8 < 64) {
#pragma unroll
            for (int j = 0; j < 8; ++j)
                g[j] = *(const float4*)(fb + (size_t)(cg + 8 + j) * HW);
        }
#pragma unroll
        for (int j = 0; j < 8; ++j) {
            const float4 fv = f[j];
            ss.x = fmaf(fv.x, fv.x, ss.x); ss.y = fmaf(fv.y, fv.y, ss.y);
            ss.z = fmaf(fv.z, fv.z, ss.z); ss.w = fmaf(fv.w, fv.w, ss.w);
        }
#pragma unroll
        for (int k = 0; k < K; ++k) {
            const float4 wa = *(const float4*)&w[k * 64 + cg];
            const float4 wb = *(const float4*)&w[k * 64 + cg + 4];
            float4 d = dot[k];
            d.x = fmaf(f[0].x, wa.x, d.x); d.y = fmaf(f[0].y, wa.x, d.y);
            d.z = fmaf(f[0].z, wa.x, d.z); d.w = fmaf(f[0].w, wa.x, d.w);
            d.x = fmaf(f[1].x, wa.y, d.x); d.y = fmaf(f[1].y, wa.y, d.y);
            d.z = fmaf(f[1].z, wa.y, d.z); d.w = fmaf(f[1].w, wa.y, d.w);
            d.x = fmaf(f[2].x, wa.z, d.x); d.y = fmaf(f[2].y, wa.z, d.y);
            d.z = fmaf(f[2].z, wa.z, d.z); d.w = fmaf(f[2].w, wa.z, d.w);
            d.x = fmaf(f[3].x, wa.w, d.x); d.y = fmaf(f[3].y, wa.w, d.y);
            d.z = fmaf(f[3].z, wa.w, d.z); d.w = fmaf(f[3].w, wa.w, d.w);
            d.x = fmaf(f[4].x, wb.x, d.x); d.y = fmaf(f[4].y, wb.x, d.y);
            d.z = fmaf(f[4].z, wb.x, d.z); d.w = fmaf(f[4].w, wb.x, d.w);
            d.x = fmaf(f[5].x, wb.y, d.x); d.y = fmaf(f[5].y, wb.y, d.y);
            d.z = fmaf(f[5].z, wb.y, d.z); d.w = fmaf(f[5].w, wb.y, d.w);
            d.x = fmaf(f[6].x, wb.z, d.x); d.y = fmaf(f[6].y, wb.z, d.y);
            d.z = fmaf(f[6].z, wb.z, d.z); d.w = fmaf(f[6].w, wb.z, d.w);
            d.x = fmaf(f[7].x, wb.w, d.x); d.y = fmaf(f[7].y, wb.w, d.y);
            d.z = fmaf(f[7].z, wb.w, d.z); d.w = fmaf(f[7].w, wb.w, d.w);
            dot[k] = d;
        }
        if (cg + 8 < 64) {
#pragma unroll
            for (int j = 0; j < 8; ++j) f[j] = g[j];
        }
    }

    float ls = 0.0f;
    float* dp = (float*)&dot[0];
    const float* sp = (const float*)&ss;
#pragma unroll
    for (int comp = 0; comp < 4; ++comp) {
        const float sc = TAUINV / fmaxf(sqrtf(sp[comp]), EPS);
        float mx = -1e30f;
#pragma unroll
        for (int k = 0; k < K; ++k) {
            dp[k * 4 + comp] *= sc;
            mx = fmaxf(mx, dp[k * 4 + comp]);
        }
        float se = 0.0f;
#pragma unroll
        for (int k = 0; k < K; ++k) se += expf(dp[k * 4 + comp] - mx);
        const float logZ = mx + logf(se);
        const unsigned m = marr[comp];
        ls += (float)__popc(m) * logZ;
#pragma unroll
        for (int k = 0; k < K; ++k) {
            const int s = ((int)(m << (31 - k))) >> 31;
            ls -= __int_as_float(s & __float_as_int(dp[k * 4 + comp]));
        }
    }

    ls = wave_reduce_f32(ls);
    if ((tid & 63) == 0) atomicAdd(loss_sum, ls);
}

// ---------------- Kernel 4: finalize --------------------------------------
__global__ void k4_final(const float* __restrict__ loss_sum,
                         const unsigned* __restrict__ num_pos,
                         float* __restrict__ out)
{
    out[0] = loss_sum[0] / (float)num_pos[0];
}

// ---------------- launch ---------------------------------------------------
extern "C" void kernel_launch(void* const* d_in, const int* in_sizes, int n_in,
                              void* d_out, int out_size, void* d_ws, size_t ws_size,
                              hipStream_t stream)
{
    const float* feat = (const float*)d_in[0];
    const int*   gt   = (const int*)d_in[1];
    float*       out  = (float*)d_out;

    char* ws = (char*)d_ws;
    unsigned* num_pos  = (unsigned*)(ws + 0);
    float*    loss_sum = (float*)(ws + 4);
    float*    k0p      = (float*)(ws + 256);    // [32][64]
    float*    k0n      = (float*)(ws + 8448);   // [19][64]
    unsigned* pm       = (unsigned*)(ws + 65536);

    hipMemsetAsync(d_ws, 0, 16384, stream);   // zero num_pos/loss_sum/k0p

    k1_proto<<<G1, 256, 0, stream>>>(feat, gt, pm, k0p, num_pos);
    k2_norm <<<1,  256, 0, stream>>>(k0p, k0n);
    k3_loss <<<NPIX / 1024, 256, 0, stream>>>(feat, gt, pm, k0n, loss_sum);
    k4_final<<<1, 1, 0, stream>>>(loss_sum, num_pos, out);
}